// Round 6
// baseline (1210.988 us; speedup 1.0000x reference)
//
#include <hip/hip_runtime.h>
#include <math.h>

#define B_ 16
#define C_ 3
#define H_ 320
#define W_ 448
#define HW_ (H_*W_)
#define NITERS_ 5
#define LAMBDA_ 0.01f
#define HUBER_ 0.1f
#define EPS_ 1e-6f

#define BPB 112       // blocks per batch (1792 total = 7 blocks/CU at 8-cap)
#define CHUNK 1280    // pixels per block; 112*1280 == H*W
#define TPB 256
#define PPT 5         // pixels per thread, looped (NOT unrolled -> low VGPR)

#define PARTIALS_OFF 2048

// ---------------- SE(3) exp in double ----------------
__device__ __host__ inline void se3_exp_d(const double xi[6], double T[16]) {
    double vx = xi[0], vy = xi[1], vz = xi[2];
    double wx = xi[3], wy = xi[4], wz = xi[5];
    double th2  = wx*wx + wy*wy + wz*wz;
    double th2c = th2 > 1e-16 ? th2 : 1e-16;
    double th   = sqrt(th2c);
    bool   sm   = th2 < 1e-10;
    double A  = sm ? (1.0 - th2*(1.0/6.0))   : (sin(th)/th);
    double Bc = sm ? (0.5 - th2*(1.0/24.0))  : ((1.0 - cos(th))/th2c);
    double Cc = sm ? (1.0/6.0 - th2*(1.0/120.0)) : ((1.0 - A)/th2c);
    double K[9]  = {0.0,-wz,wy,  wz,0.0,-wx,  -wy,wx,0.0};
    double K2[9];
    #pragma unroll
    for (int i = 0; i < 3; ++i)
        #pragma unroll
        for (int j = 0; j < 3; ++j) {
            double s = 0.0;
            #pragma unroll
            for (int k = 0; k < 3; ++k) s += K[i*3+k]*K[k*3+j];
            K2[i*3+j] = s;
        }
    double R[9], V[9];
    #pragma unroll
    for (int i = 0; i < 9; ++i) {
        double I = (i == 0 || i == 4 || i == 8) ? 1.0 : 0.0;
        R[i] = I + A*K[i]  + Bc*K2[i];
        V[i] = I + Bc*K[i] + Cc*K2[i];
    }
    double tx = V[0]*vx + V[1]*vy + V[2]*vz;
    double ty = V[3]*vx + V[4]*vy + V[5]*vz;
    double tz = V[6]*vx + V[7]*vy + V[8]*vz;
    T[0]=R[0]; T[1]=R[1]; T[2] =R[2]; T[3] =tx;
    T[4]=R[3]; T[5]=R[4]; T[6] =R[5]; T[7] =ty;
    T[8]=R[6]; T[9]=R[7]; T[10]=R[8]; T[11]=tz;
    T[12]=0.0; T[13]=0.0; T[14]=0.0;  T[15]=1.0;
}

// ---------------- init: T = se3_exp(pose_twist) ----------------
__global__ void init_kernel(const float* __restrict__ pose,
                            float* __restrict__ Tcur, float* __restrict__ Tinit) {
    int b = threadIdx.x;
    if (b >= B_) return;
    double xi[6];
    #pragma unroll
    for (int k = 0; k < 6; ++k) xi[k] = (double)pose[b*6+k];
    double T[16];
    se3_exp_d(xi, T);
    #pragma unroll
    for (int k = 0; k < 16; ++k) {
        float f = (float)T[k];
        Tcur[b*16+k]  = f;
        Tinit[b*16+k] = f;
    }
}

// ---------------- per-pixel GN accumulation (register-frugal, 8 waves/EU) ----
// Targeting the VGPR<=64 occupancy tier (m69 cliff): no unroll, no preload
// arrays, per-channel fused stencil->accumulate. WRITE_SIZE is the spill
// tripwire (R2/R3: launch-bounds-induced spills cost ~100MB writes).
__global__ __launch_bounds__(TPB, 8)
void pixel_kernel(const float* __restrict__ I0, const float* __restrict__ I1,
                  const float* __restrict__ invD0, const float* __restrict__ invD1,
                  const float* __restrict__ intr,
                  const float* __restrict__ Tcur, const float* __restrict__ Tinit,
                  float* __restrict__ partials)
{
    // XCD-aware swizzle (bijective, 1792 % 8 == 0): contiguous chunks per XCD.
    const int nwg = B_*BPB;
    const int bid = blockIdx.x;
    const int swz = (bid & 7) * (nwg >> 3) + (bid >> 3);
    const int b   = swz / BPB;
    const int blk = swz % BPB;

    const float fx = intr[b*4+0], fy = intr[b*4+1];
    const float cx = intr[b*4+2], cy = intr[b*4+3];
    const float inv_fx = 1.0f/fx, inv_fy = 1.0f/fy;

    const float* Tc = Tcur  + b*16;
    const float* Ti = Tinit + b*16;
    const float Rc00=Tc[0], Rc01=Tc[1], Rc02=Tc[2],  tcx=Tc[3];
    const float Rc10=Tc[4], Rc11=Tc[5], Rc12=Tc[6],  tcy=Tc[7];
    const float Rc20=Tc[8], Rc21=Tc[9], Rc22=Tc[10], tcz=Tc[11];
    const float Ri00=Ti[0], Ri01=Ti[1], Ri02=Ti[2],  tix=Ti[3];
    const float Ri10=Ti[4], Ri11=Ti[5], Ri12=Ti[6],  tiy=Ti[7];
    const float Ri20=Ti[8], Ri21=Ti[9], Ri22=Ti[10], tiz=Ti[11];

    const float* P0 = I0    + (size_t)b*C_*HW_;
    const float* P1 = I1    + (size_t)b*C_*HW_;
    const float* D0 = invD0 + (size_t)b*HW_;
    const float* D1 = invD1 + (size_t)b*HW_;

    float acc[27];
    #pragma unroll
    for (int k = 0; k < 27; ++k) acc[k] = 0.0f;

    const int base = blk*CHUNK + (int)threadIdx.x;

    #pragma unroll 1
    for (int i5 = 0; i5 < PPT; ++i5) {
        const int p = base + i5*TPB;
        const int vcoord = p / W_;
        const int ucoord = p - vcoord*W_;

        const float iD1 = D1[p];
        const float iD  = fmaxf(iD1, EPS_);
        const float z1  = 1.0f / iD;
        const float x1  = ((float)ucoord - cx)*inv_fx * z1;
        const float y1  = ((float)vcoord - cy)*inv_fy * z1;

        // current warp
        const float Xc0 = Rc00*x1 + Rc01*y1 + Rc02*z1 + tcx;
        const float Xc1 = Rc10*x1 + Rc11*y1 + Rc12*z1 + tcy;
        const float Xc2 = Rc20*x1 + Rc21*y1 + Rc22*z1 + tcz;
        const float z0s = (fabsf(Xc2) > EPS_) ? Xc2 : EPS_;
        const float izc = 1.0f / z0s;
        const float u0  = fx*Xc0*izc + cx;
        const float v0  = fy*Xc1*izc + cy;
        const bool valid = (Xc2 > EPS_) && (iD1 > EPS_);
        const bool inb   = (u0 > 0.0f) && (u0 < (float)(W_-1)) &&
                           (v0 > 0.0f) && (v0 < (float)(H_-1));
        const bool vm = valid && inb;

        // initial-T projection for Jacobian (fixed linearization point)
        const float Xi0 = Ri00*x1 + Ri01*y1 + Ri02*z1 + tix;
        const float Xi1 = Ri10*x1 + Ri11*y1 + Ri12*z1 + tiy;
        const float Xi2 = Ri20*x1 + Ri21*y1 + Ri22*z1 + tiz;
        const float zis = (fabsf(Xi2) > EPS_) ? Xi2 : EPS_;
        const float izi = 1.0f / zis;
        const float aJ = fx*izi;
        const float cJ = -fx*Xi0*izi*izi;
        const float bJ = fy*izi;
        const float dJ = -fy*Xi1*izi*izi;
        const float Jw0[6] = {aJ, 0.0f, cJ, cJ*Xi1, aJ*Xi2 - cJ*Xi0, -aJ*Xi1};
        const float Jw1[6] = {0.0f, bJ, dJ, dJ*Xi1 - bJ*Xi2, -dJ*Xi0, bJ*Xi0};
        const float Jtz[6] = {0.0f, 0.0f, 1.0f, Xi1, -Xi0, 0.0f};

        // normalized grid (clipped), back to pixel coords -- mirror reference
        const float gx = fminf(fmaxf((u0/(float)(W_-1) - 0.5f)*2.0f, -2.0f), 2.0f);
        const float gy = fminf(fmaxf((v0/(float)(H_-1) - 0.5f)*2.0f, -2.0f), 2.0f);
        const float ix = (gx + 1.0f)*0.5f*(float)(W_-1);
        const float iy = (gy + 1.0f)*0.5f*(float)(H_-1);
        const float x0f = floorf(ix), y0f = floorf(iy);
        const float wx1 = ix - x0f,  wy1 = iy - y0f;
        const float wx0 = 1.0f - wx1, wy0 = 1.0f - wy1;
        const float w00 = wx0*wy0, w10 = wx1*wy0, w01 = wx0*wy1, w11 = wx1*wy1;

        const bool fast = (x0f >= 1.0f) && (x0f <= (float)(W_-3)) &&
                          (y0f >= 1.0f) && (y0f <= (float)(H_-3));
        const bool allfast = __all((int)fast);

        // per-channel fused stencil -> accumulate (only ~12 stencil regs live)
        #pragma unroll 1
        for (int c = 0; c < 4; ++c) {
            float sv, sgx, sgy;
            const float* pc = (c < 3) ? (P0 + c*HW_) : D0;

            if (allfast) {
                const int off = (int)y0f*W_ + (int)x0f;
                const float* pr = pc + off;
                const float am0 = pr[-1],    v00 = pr[0],     v10 = pr[1],     ap0 = pr[2];
                const float am1 = pr[W_-1],  v01 = pr[W_],    v11 = pr[W_+1],  ap1 = pr[W_+2];
                const float um0 = pr[-W_],   um1 = pr[-W_+1];
                const float dm0 = pr[2*W_],  dm1 = pr[2*W_+1];
                sv  = w00*v00 + w10*v10 + w01*v01 + w11*v11;
                sgx = 0.5f*(w00*(v10 - am0) + w10*(ap0 - v00) +
                            w01*(v11 - am1) + w11*(ap1 - v01));
                sgy = 0.5f*(w00*(v01 - um0) + w10*(v11 - um1) +
                            w01*(dm0 - v00) + w11*(dm1 - v10));
            } else {
                float tv = 0.0f, tx_ = 0.0f, ty_ = 0.0f;
                #pragma unroll
                for (int tap = 0; tap < 4; ++tap) {
                    const float xf = x0f + (float)(tap & 1);
                    const float yf = y0f + (float)(tap >> 1);
                    const float wgt = ((tap & 1) ? wx1 : wx0) * ((tap >> 1) ? wy1 : wy0);
                    const float m = (xf >= 0.0f && xf <= (float)(W_-1) &&
                                     yf >= 0.0f && yf <= (float)(H_-1)) ? wgt : 0.0f;
                    int xc = (int)xf; xc = xc < 0 ? 0 : (xc > W_-1 ? W_-1 : xc);
                    int yc = (int)yf; yc = yc < 0 ? 0 : (yc > H_-1 ? H_-1 : yc);
                    const int xp = (xc+1 > W_-1) ? W_-1 : xc+1;
                    const int xm = (xc-1 < 0) ? 0 : xc-1;
                    const int row  = yc*W_;
                    const int rowp = ((yc+1 > H_-1) ? H_-1 : yc+1)*W_;
                    const int rowm = ((yc-1 < 0) ? 0 : yc-1)*W_;
                    tv  += m * pc[row+xc];
                    tx_ += m * 0.5f*(pc[row+xp]  - pc[row+xm]);
                    ty_ += m * 0.5f*(pc[rowp+xc] - pc[rowm+xc]);
                }
                sv = tv; sgx = tx_; sgy = ty_;
            }

            float r, w, Jfac;
            if (c < 3) {
                r = vm ? (P1[c*HW_ + p] - sv) : 1e-6f;
                w = fminf(1.0f, HUBER_ / fmaxf(fabsf(r), EPS_));
                Jfac = 0.0f;  // no Jtz term
            } else {
                r = LAMBDA_ * (vm ? (izc - sv) : 1e-6f);
                w = fminf(1.0f, HUBER_ / fmaxf(fabsf(r), EPS_));
                Jfac = 1.0f;  // include Jtz, scale LAMBDA
            }
            float J[6];
            #pragma unroll
            for (int k = 0; k < 6; ++k) {
                const float base_ = sgx*Jw0[k] + sgy*Jw1[k];
                J[k] = (c < 3) ? -base_ : LAMBDA_*(Jtz[k] - base_);
            }
            (void)Jfac;
            const float wr = w*r;
            int idx = 0;
            #pragma unroll
            for (int i2 = 0; i2 < 6; ++i2) {
                const float wJi = w*J[i2];
                #pragma unroll
                for (int j2 = i2; j2 < 6; ++j2)
                    acc[idx++] += wJi*J[j2];
                acc[21+i2] += wr*J[i2];
            }
        }
    }

    // wave (64-lane) reduction in float
    #pragma unroll
    for (int off = 32; off >= 1; off >>= 1) {
        #pragma unroll
        for (int k = 0; k < 27; ++k)
            acc[k] += __shfl_down(acc[k], off);
    }
    __shared__ float red[TPB/64][27];
    const int lane = threadIdx.x & 63;
    const int wid  = threadIdx.x >> 6;
    if (lane == 0) {
        #pragma unroll
        for (int k = 0; k < 27; ++k) red[wid][k] = acc[k];
    }
    __syncthreads();
    if (threadIdx.x < 27) {
        float s = red[0][threadIdx.x] + red[1][threadIdx.x]
                + red[2][threadIdx.x] + red[3][threadIdx.x];
        partials[((size_t)b*BPB + blk)*27 + threadIdx.x] = s;
    }
}

// ---------------- reduce partials, solve 6x6, update T ----------------
__global__ void solve_kernel(const float* __restrict__ partials,
                             float* __restrict__ Tcur, float* __restrict__ out)
{
    const int b = blockIdx.x;
    __shared__ double S[27];
    const int t = threadIdx.x;
    if (t < 27) {
        double s = 0.0;
        const float* pp = partials + (size_t)b*BPB*27 + t;
        for (int blk = 0; blk < BPB; ++blk) s += (double)pp[blk*27];
        S[t] = s;
    }
    __syncthreads();
    if (t == 0) {
        double Hm[6][6], rhs[6];
        int idx = 0;
        for (int i = 0; i < 6; ++i)
            for (int j = i; j < 6; ++j) { Hm[i][j] = S[idx]; Hm[j][i] = S[idx]; ++idx; }
        double tr = 0.0;
        for (int i = 0; i < 6; ++i) tr += Hm[i][i];
        const double damp = tr*1e-6;
        for (int i = 0; i < 6; ++i) Hm[i][i] += damp;
        for (int i = 0; i < 6; ++i) rhs[i] = S[21+i];

        double M[6][7];
        for (int i = 0; i < 6; ++i) {
            for (int j = 0; j < 6; ++j) M[i][j] = Hm[i][j];
            M[i][6] = rhs[i];
        }
        for (int col = 0; col < 6; ++col) {
            int piv = col; double mx = fabs(M[col][col]);
            for (int r2 = col+1; r2 < 6; ++r2) {
                double a2 = fabs(M[r2][col]);
                if (a2 > mx) { mx = a2; piv = r2; }
            }
            if (piv != col)
                for (int j = col; j < 7; ++j) {
                    double tmp = M[col][j]; M[col][j] = M[piv][j]; M[piv][j] = tmp;
                }
            const double inv = 1.0 / M[col][col];
            for (int r2 = col+1; r2 < 6; ++r2) {
                const double f = M[r2][col]*inv;
                for (int j = col; j < 7; ++j) M[r2][j] -= f*M[col][j];
            }
        }
        double xi[6];
        for (int i = 5; i >= 0; --i) {
            double s2 = M[i][6];
            for (int j = i+1; j < 6; ++j) s2 -= M[i][j]*xi[j];
            xi[i] = s2 / M[i][i];
        }
        double nxi[6];
        for (int i = 0; i < 6; ++i) nxi[i] = -xi[i];
        double E[16];
        se3_exp_d(nxi, E);

        double Tc[16];
        for (int k = 0; k < 16; ++k) Tc[k] = (double)Tcur[b*16+k];
        for (int i = 0; i < 4; ++i)
            for (int j = 0; j < 4; ++j) {
                double s2 = 0.0;
                for (int k = 0; k < 4; ++k) s2 += Tc[i*4+k]*E[k*4+j];
                const float f = (float)s2;
                Tcur[b*16 + i*4 + j] = f;
                out[b*16 + i*4 + j]  = f;
            }
    }
}

extern "C" void kernel_launch(void* const* d_in, const int* in_sizes, int n_in,
                              void* d_out, int out_size, void* d_ws, size_t ws_size,
                              hipStream_t stream) {
    const float* pose  = (const float*)d_in[0];
    const float* I0    = (const float*)d_in[1];
    const float* I1    = (const float*)d_in[2];
    const float* invD0 = (const float*)d_in[3];
    const float* invD1 = (const float*)d_in[4];
    const float* intr  = (const float*)d_in[5];
    float* out = (float*)d_out;

    float* Tcur     = (float*)d_ws;
    float* Tinit    = Tcur + 256;
    float* partials = (float*)((char*)d_ws + PARTIALS_OFF);

    hipLaunchKernelGGL(init_kernel, dim3(1), dim3(64), 0, stream, pose, Tcur, Tinit);
    for (int it = 0; it < NITERS_; ++it) {
        hipLaunchKernelGGL(pixel_kernel, dim3(B_*BPB), dim3(TPB), 0, stream,
                           I0, I1, invD0, invD1, intr, Tcur, Tinit, partials);
        hipLaunchKernelGGL(solve_kernel, dim3(B_), dim3(64), 0, stream,
                           partials, Tcur, out);
    }
}

// Round 7
// 536.065 us; speedup vs baseline: 2.2590x; 2.2590x over previous
//
#include <hip/hip_runtime.h>
#include <math.h>

#define B_ 16
#define C_ 3
#define H_ 320
#define W_ 448
#define HW_ (H_*W_)
#define NITERS_ 5
#define LAMBDA_ 0.01f
#define HUBER_ 0.1f
#define EPS_ 1e-6f

#define BPB 112       // blocks per batch (1792 total)
#define CHUNK 1280    // pixels per block; 112*1280 == H*W
#define TPB 256
#define PPT 5         // pixels per thread, fully unrolled (branchless bodies)

#define PARTIALS_OFF 2048

// ---------------- SE(3) exp in double ----------------
__device__ __host__ inline void se3_exp_d(const double xi[6], double T[16]) {
    double vx = xi[0], vy = xi[1], vz = xi[2];
    double wx = xi[3], wy = xi[4], wz = xi[5];
    double th2  = wx*wx + wy*wy + wz*wz;
    double th2c = th2 > 1e-16 ? th2 : 1e-16;
    double th   = sqrt(th2c);
    bool   sm   = th2 < 1e-10;
    double A  = sm ? (1.0 - th2*(1.0/6.0))   : (sin(th)/th);
    double Bc = sm ? (0.5 - th2*(1.0/24.0))  : ((1.0 - cos(th))/th2c);
    double Cc = sm ? (1.0/6.0 - th2*(1.0/120.0)) : ((1.0 - A)/th2c);
    double K[9]  = {0.0,-wz,wy,  wz,0.0,-wx,  -wy,wx,0.0};
    double K2[9];
    #pragma unroll
    for (int i = 0; i < 3; ++i)
        #pragma unroll
        for (int j = 0; j < 3; ++j) {
            double s = 0.0;
            #pragma unroll
            for (int k = 0; k < 3; ++k) s += K[i*3+k]*K[k*3+j];
            K2[i*3+j] = s;
        }
    double R[9], V[9];
    #pragma unroll
    for (int i = 0; i < 9; ++i) {
        double I = (i == 0 || i == 4 || i == 8) ? 1.0 : 0.0;
        R[i] = I + A*K[i]  + Bc*K2[i];
        V[i] = I + Bc*K[i] + Cc*K2[i];
    }
    double tx = V[0]*vx + V[1]*vy + V[2]*vz;
    double ty = V[3]*vx + V[4]*vy + V[5]*vz;
    double tz = V[6]*vx + V[7]*vy + V[8]*vz;
    T[0]=R[0]; T[1]=R[1]; T[2] =R[2]; T[3] =tx;
    T[4]=R[3]; T[5]=R[4]; T[6] =R[5]; T[7] =ty;
    T[8]=R[6]; T[9]=R[7]; T[10]=R[8]; T[11]=tz;
    T[12]=0.0; T[13]=0.0; T[14]=0.0;  T[15]=1.0;
}

// ---------------- init: T = se3_exp(pose_twist) ----------------
__global__ void init_kernel(const float* __restrict__ pose,
                            float* __restrict__ Tcur, float* __restrict__ Tinit) {
    int b = threadIdx.x;
    if (b >= B_) return;
    double xi[6];
    #pragma unroll
    for (int k = 0; k < 6; ++k) xi[k] = (double)pose[b*6+k];
    double T[16];
    se3_exp_d(xi, T);
    #pragma unroll
    for (int k = 0; k < 16; ++k) {
        float f = (float)T[k];
        Tcur[b*16+k]  = f;
        Tinit[b*16+k] = f;
    }
}

// ---------------- per-pixel GN accumulation (branchless stencil) ----------
// NO __launch_bounds__ min-waves: R2/R3/R6 proved any cap -> scratch spills
// (R6: 475 MB writes). Natural alloc ~108-130 VGPR, 4 waves/SIMD.
// Stencil is a single branchless path: each of the 12 unique points uses
// independently-clamped row/col indices; identical to reference for every
// unmasked tap, masked taps (m=0) read in-bounds don't-care values.
__global__ __launch_bounds__(TPB)
void pixel_kernel(const float* __restrict__ I0, const float* __restrict__ I1,
                  const float* __restrict__ invD0, const float* __restrict__ invD1,
                  const float* __restrict__ intr,
                  const float* __restrict__ Tcur, const float* __restrict__ Tinit,
                  float* __restrict__ partials)
{
    // XCD-aware swizzle (bijective, 1792 % 8 == 0): contiguous chunks per XCD.
    const int nwg = B_*BPB;
    const int bid = blockIdx.x;
    const int swz = (bid & 7) * (nwg >> 3) + (bid >> 3);
    const int b   = swz / BPB;
    const int blk = swz % BPB;

    const float fx = intr[b*4+0], fy = intr[b*4+1];
    const float cx = intr[b*4+2], cy = intr[b*4+3];
    const float inv_fx = 1.0f/fx, inv_fy = 1.0f/fy;

    const float* Tc = Tcur  + b*16;
    const float* Ti = Tinit + b*16;
    const float Rc00=Tc[0], Rc01=Tc[1], Rc02=Tc[2],  tcx=Tc[3];
    const float Rc10=Tc[4], Rc11=Tc[5], Rc12=Tc[6],  tcy=Tc[7];
    const float Rc20=Tc[8], Rc21=Tc[9], Rc22=Tc[10], tcz=Tc[11];
    const float Ri00=Ti[0], Ri01=Ti[1], Ri02=Ti[2],  tix=Ti[3];
    const float Ri10=Ti[4], Ri11=Ti[5], Ri12=Ti[6],  tiy=Ti[7];
    const float Ri20=Ti[8], Ri21=Ti[9], Ri22=Ti[10], tiz=Ti[11];

    const float* P0 = I0    + (size_t)b*C_*HW_;
    const float* P1 = I1    + (size_t)b*C_*HW_;
    const float* D0 = invD0 + (size_t)b*HW_;
    const float* D1 = invD1 + (size_t)b*HW_;

    float acc[27];
    #pragma unroll
    for (int k = 0; k < 27; ++k) acc[k] = 0.0f;

    const int base = blk*CHUNK + (int)threadIdx.x;

    // up-front preload of all linear-address data (R4-proven)
    float d1v[PPT];
    float p1v[C_][PPT];
    #pragma unroll
    for (int i = 0; i < PPT; ++i) d1v[i] = D1[base + i*TPB];
    #pragma unroll
    for (int c = 0; c < C_; ++c)
        #pragma unroll
        for (int i = 0; i < PPT; ++i) p1v[c][i] = P1[c*HW_ + base + i*TPB];

    auto body = [&](int i5) {
        const int p = base + i5*TPB;
        const int vcoord = p / W_;
        const int ucoord = p - vcoord*W_;

        const float iD1 = d1v[i5];
        const float iD  = fmaxf(iD1, EPS_);
        const float z1  = 1.0f / iD;
        const float x1  = ((float)ucoord - cx)*inv_fx * z1;
        const float y1  = ((float)vcoord - cy)*inv_fy * z1;

        // current warp
        const float Xc0 = Rc00*x1 + Rc01*y1 + Rc02*z1 + tcx;
        const float Xc1 = Rc10*x1 + Rc11*y1 + Rc12*z1 + tcy;
        const float Xc2 = Rc20*x1 + Rc21*y1 + Rc22*z1 + tcz;
        const float z0s = (fabsf(Xc2) > EPS_) ? Xc2 : EPS_;
        const float izc = 1.0f / z0s;
        const float u0  = fx*Xc0*izc + cx;
        const float v0  = fy*Xc1*izc + cy;
        const bool valid = (Xc2 > EPS_) && (iD1 > EPS_);
        const bool inb   = (u0 > 0.0f) && (u0 < (float)(W_-1)) &&
                           (v0 > 0.0f) && (v0 < (float)(H_-1));
        const bool vm = valid && inb;

        // initial-T projection for Jacobian (fixed linearization point)
        const float Xi0 = Ri00*x1 + Ri01*y1 + Ri02*z1 + tix;
        const float Xi1 = Ri10*x1 + Ri11*y1 + Ri12*z1 + tiy;
        const float Xi2 = Ri20*x1 + Ri21*y1 + Ri22*z1 + tiz;
        const float zis = (fabsf(Xi2) > EPS_) ? Xi2 : EPS_;
        const float izi = 1.0f / zis;
        const float aJ = fx*izi;
        const float cJ = -fx*Xi0*izi*izi;
        const float bJ = fy*izi;
        const float dJ = -fy*Xi1*izi*izi;
        const float Jw0[6] = {aJ, 0.0f, cJ, cJ*Xi1, aJ*Xi2 - cJ*Xi0, -aJ*Xi1};
        const float Jw1[6] = {0.0f, bJ, dJ, dJ*Xi1 - bJ*Xi2, -dJ*Xi0, bJ*Xi0};
        const float Jtz[6] = {0.0f, 0.0f, 1.0f, Xi1, -Xi0, 0.0f};

        // normalized grid (clipped), back to pixel coords -- mirror reference
        const float gx = fminf(fmaxf((u0/(float)(W_-1) - 0.5f)*2.0f, -2.0f), 2.0f);
        const float gy = fminf(fmaxf((v0/(float)(H_-1) - 0.5f)*2.0f, -2.0f), 2.0f);
        const float ix = (gx + 1.0f)*0.5f*(float)(W_-1);
        const float iy = (gy + 1.0f)*0.5f*(float)(H_-1);
        const float x0f = floorf(ix), y0f = floorf(iy);
        const float wx1 = ix - x0f,  wy1 = iy - y0f;
        const float wx0 = 1.0f - wx1, wy0 = 1.0f - wy1;

        // per-tap masks (reference semantics: tap inside [0,W-1]x[0,H-1])
        const bool bx0 = (x0f >= 0.0f)  && (x0f <= (float)(W_-1));
        const bool bx1 = (x0f >= -1.0f) && (x0f <= (float)(W_-2));
        const bool by0 = (y0f >= 0.0f)  && (y0f <= (float)(H_-1));
        const bool by1 = (y0f >= -1.0f) && (y0f <= (float)(H_-2));
        const float m00 = (bx0 && by0) ? wx0*wy0 : 0.0f;
        const float m10 = (bx1 && by0) ? wx1*wy0 : 0.0f;
        const float m01 = (bx0 && by1) ? wx0*wy1 : 0.0f;
        const float m11 = (bx1 && by1) ? wx1*wy1 : 0.0f;

        // independently clamped rows/cols (grid clip bounds ix in [-224,671])
        const int x0i = (int)x0f;
        const int y0i = (int)y0f;
        const int cA = min(max(x0i-1, 0), W_-1);
        const int c0 = min(max(x0i,   0), W_-1);
        const int c1 = min(max(x0i+1, 0), W_-1);
        const int cB = min(max(x0i+2, 0), W_-1);
        const int oA = min(max(y0i-1, 0), H_-1) * W_;
        const int o0 = min(max(y0i,   0), H_-1) * W_;
        const int o1 = min(max(y0i+1, 0), H_-1) * W_;
        const int oB = min(max(y0i+2, 0), H_-1) * W_;

        // 4 channels: RGB photometric + invD0 depth, each 12 shared points
        #pragma unroll
        for (int c = 0; c < 4; ++c) {
            const float* pc = (c < 3) ? (P0 + c*HW_) : D0;
            const float fA0 = pc[o0+cA], f00 = pc[o0+c0], f10 = pc[o0+c1], fB0 = pc[o0+cB];
            const float fA1 = pc[o1+cA], f01 = pc[o1+c0], f11 = pc[o1+c1], fB1 = pc[o1+cB];
            const float u0_ = pc[oA+c0], u1_ = pc[oA+c1];
            const float d0_ = pc[oB+c0], d1_ = pc[oB+c1];

            const float sv  = m00*f00 + m10*f10 + m01*f01 + m11*f11;
            const float sgx = 0.5f*(m00*(f10-fA0) + m10*(fB0-f00) +
                                    m01*(f11-fA1) + m11*(fB1-f01));
            const float sgy = 0.5f*(m00*(f01-u0_) + m10*(f11-u1_) +
                                    m01*(d0_-f00) + m11*(d1_-f10));

            float r, w;
            float J[6];
            if (c < 3) {
                r = vm ? (p1v[c][i5] - sv) : 1e-6f;
                w = fminf(1.0f, HUBER_ / fmaxf(fabsf(r), EPS_));
                #pragma unroll
                for (int k = 0; k < 6; ++k)
                    J[k] = -(sgx*Jw0[k] + sgy*Jw1[k]);
            } else {
                r = LAMBDA_ * (vm ? (izc - sv) : 1e-6f);
                w = fminf(1.0f, HUBER_ / fmaxf(fabsf(r), EPS_));
                #pragma unroll
                for (int k = 0; k < 6; ++k)
                    J[k] = LAMBDA_ * (Jtz[k] - (sgx*Jw0[k] + sgy*Jw1[k]));
            }
            const float wr = w*r;
            int idx = 0;
            #pragma unroll
            for (int i2 = 0; i2 < 6; ++i2) {
                const float wJi = w*J[i2];
                #pragma unroll
                for (int j2 = i2; j2 < 6; ++j2)
                    acc[idx++] += wJi*J[j2];
                acc[21+i2] += wr*J[i2];
            }
        }
    };

    #pragma unroll
    for (int i5 = 0; i5 < PPT; ++i5)
        body(i5);

    // wave (64-lane) reduction in float
    #pragma unroll
    for (int off = 32; off >= 1; off >>= 1) {
        #pragma unroll
        for (int k = 0; k < 27; ++k)
            acc[k] += __shfl_down(acc[k], off);
    }
    __shared__ float red[TPB/64][27];
    const int lane = threadIdx.x & 63;
    const int wid  = threadIdx.x >> 6;
    if (lane == 0) {
        #pragma unroll
        for (int k = 0; k < 27; ++k) red[wid][k] = acc[k];
    }
    __syncthreads();
    if (threadIdx.x < 27) {
        float s = red[0][threadIdx.x] + red[1][threadIdx.x]
                + red[2][threadIdx.x] + red[3][threadIdx.x];
        partials[((size_t)b*BPB + blk)*27 + threadIdx.x] = s;
    }
}

// ---------------- reduce partials, solve 6x6, update T ----------------
__global__ void solve_kernel(const float* __restrict__ partials,
                             float* __restrict__ Tcur, float* __restrict__ out)
{
    const int b = blockIdx.x;
    __shared__ double S[27];
    const int t = threadIdx.x;
    if (t < 27) {
        double s = 0.0;
        const float* pp = partials + (size_t)b*BPB*27 + t;
        for (int blk = 0; blk < BPB; ++blk) s += (double)pp[blk*27];
        S[t] = s;
    }
    __syncthreads();
    if (t == 0) {
        double Hm[6][6], rhs[6];
        int idx = 0;
        for (int i = 0; i < 6; ++i)
            for (int j = i; j < 6; ++j) { Hm[i][j] = S[idx]; Hm[j][i] = S[idx]; ++idx; }
        double tr = 0.0;
        for (int i = 0; i < 6; ++i) tr += Hm[i][i];
        const double damp = tr*1e-6;
        for (int i = 0; i < 6; ++i) Hm[i][i] += damp;
        for (int i = 0; i < 6; ++i) rhs[i] = S[21+i];

        double M[6][7];
        for (int i = 0; i < 6; ++i) {
            for (int j = 0; j < 6; ++j) M[i][j] = Hm[i][j];
            M[i][6] = rhs[i];
        }
        for (int col = 0; col < 6; ++col) {
            int piv = col; double mx = fabs(M[col][col]);
            for (int r2 = col+1; r2 < 6; ++r2) {
                double a2 = fabs(M[r2][col]);
                if (a2 > mx) { mx = a2; piv = r2; }
            }
            if (piv != col)
                for (int j = col; j < 7; ++j) {
                    double tmp = M[col][j]; M[col][j] = M[piv][j]; M[piv][j] = tmp;
                }
            const double inv = 1.0 / M[col][col];
            for (int r2 = col+1; r2 < 6; ++r2) {
                const double f = M[r2][col]*inv;
                for (int j = col; j < 7; ++j) M[r2][j] -= f*M[col][j];
            }
        }
        double xi[6];
        for (int i = 5; i >= 0; --i) {
            double s2 = M[i][6];
            for (int j = i+1; j < 6; ++j) s2 -= M[i][j]*xi[j];
            xi[i] = s2 / M[i][i];
        }
        double nxi[6];
        for (int i = 0; i < 6; ++i) nxi[i] = -xi[i];
        double E[16];
        se3_exp_d(nxi, E);

        double Tc[16];
        for (int k = 0; k < 16; ++k) Tc[k] = (double)Tcur[b*16+k];
        for (int i = 0; i < 4; ++i)
            for (int j = 0; j < 4; ++j) {
                double s2 = 0.0;
                for (int k = 0; k < 4; ++k) s2 += Tc[i*4+k]*E[k*4+j];
                const float f = (float)s2;
                Tcur[b*16 + i*4 + j] = f;
                out[b*16 + i*4 + j]  = f;
            }
    }
}

extern "C" void kernel_launch(void* const* d_in, const int* in_sizes, int n_in,
                              void* d_out, int out_size, void* d_ws, size_t ws_size,
                              hipStream_t stream) {
    const float* pose  = (const float*)d_in[0];
    const float* I0    = (const float*)d_in[1];
    const float* I1    = (const float*)d_in[2];
    const float* invD0 = (const float*)d_in[3];
    const float* invD1 = (const float*)d_in[4];
    const float* intr  = (const float*)d_in[5];
    float* out = (float*)d_out;

    float* Tcur     = (float*)d_ws;
    float* Tinit    = Tcur + 256;
    float* partials = (float*)((char*)d_ws + PARTIALS_OFF);

    hipLaunchKernelGGL(init_kernel, dim3(1), dim3(64), 0, stream, pose, Tcur, Tinit);
    for (int it = 0; it < NITERS_; ++it) {
        hipLaunchKernelGGL(pixel_kernel, dim3(B_*BPB), dim3(TPB), 0, stream,
                           I0, I1, invD0, invD1, intr, Tcur, Tinit, partials);
        hipLaunchKernelGGL(solve_kernel, dim3(B_), dim3(64), 0, stream,
                           partials, Tcur, out);
    }
}